// Round 15
// baseline (4020.652 us; speedup 1.0000x reference)
//
#include <hip/hip_runtime.h>
#include <cstdint>
#include <cstddef>

#define DEVI __device__ __forceinline__

typedef __attribute__((ext_vector_type(8))) short bf16x8;
typedef __attribute__((ext_vector_type(4))) float f32x4;
typedef unsigned short ushort_t;
typedef unsigned int uint_t;

// problem dims (fixed)
constexpr int NB = 64;    // batch
constexpr int NTT = 512;  // seq len
constexpr int NI = 512;   // input feat
constexpr int NH = 1024;  // hidden
constexpr int NA = 512;   // out feat
constexpr int NG = 4096;  // 4*NH

DEVI float bf2f(ushort_t u) { union { uint_t i; float f; } v; v.i = ((uint_t)u) << 16; return v.f; }
DEVI ushort_t f2bf(float f) {
  union { float f; uint_t i; } v; v.f = f;
  uint_t x = v.i;
  return (ushort_t)((x + 0x7fffu + ((x >> 16) & 1u)) >> 16);
}

// clamped fast tanh: safe for |x| large (clamp before exp), bf16-accurate
DEVI float tanh_f(float x) {
  x = fminf(fmaxf(x, -15.f), 15.f);
  float e = __expf(2.f * x);
  return (e - 1.f) / (e + 1.f);
}

DEVI void gload_lds16(const void* g, void* l) {
  __builtin_amdgcn_global_load_lds((__attribute__((address_space(1))) void*)g,
                                   (__attribute__((address_space(3))) void*)l, 16, 0, 0);
}

// ---------------- cast fp32 -> bf16 ----------------
__global__ __launch_bounds__(256) void cast_f32_bf16(const float* __restrict__ in,
                                                     ushort_t* __restrict__ out, int n) {
  int i = (blockIdx.x * 256 + threadIdx.x) * 4;
  if (i >= n) return;
  float4 v = *(const float4*)(in + i);
  ushort4 o;
  o.x = f2bf(v.x); o.y = f2bf(v.y); o.z = f2bf(v.z); o.w = f2bf(v.w);
  *(ushort4*)(out + i) = o;
}

// ---------------- generic NT GEMM: C[M,N] = A[M,K] * B[N,K]^T ----------------
// MODE 0: fp32 out, +bias0 (fc3) | MODE 1: bf16 out, tanh (fc1) |
// MODE 2: chunked gx (chunk = 1<<TLB steps): scatter to gxc[tl][wg][b][g*16+u]
template <int MODE, int TLB>
__global__ __launch_bounds__(256) void gemm_nt(const short* __restrict__ A,
                                               const short* __restrict__ Bm,
                                               const float* __restrict__ bias0,
                                               const float* __restrict__ bias1,
                                               void* __restrict__ Cout,
                                               int M, int N, int K, int t0) {
  __shared__ short As[128 * 32];
  __shared__ short Bs[128 * 32];
  const int tid = threadIdx.x;
  const int wave = tid >> 6, lane = tid & 63;
  const int m0 = blockIdx.y * 128, n0 = blockIdx.x * 128;
  const int wr = wave >> 1, wc = wave & 1;

  f32x4 zero = {0.f, 0.f, 0.f, 0.f};
  f32x4 acc[4][4];
#pragma unroll
  for (int i = 0; i < 4; ++i)
#pragma unroll
    for (int j = 0; j < 4; ++j) acc[i][j] = zero;

  const int lrow = lane >> 2;
  const int lk = (lane & 3) * 8;

  for (int kt = 0; kt < K; kt += 32) {
#pragma unroll
    for (int c = 0; c < 2; ++c) {
      int q = wave + 4 * c;
      int row = m0 + q * 16 + lrow;
      long arow = (MODE == 2) ? ((long)(row >> TLB) * NTT + t0 + (row & ((1 << TLB) - 1)))
                              : (long)row;
      gload_lds16(A + arow * K + kt + lk, As + q * 512);
      gload_lds16(Bm + (long)(n0 + q * 16 + lrow) * K + kt + lk, Bs + q * 512);
    }
    __syncthreads();

    bf16x8 av[4], bv[4];
#pragma unroll
    for (int i = 0; i < 4; ++i) {
      int row = wr * 64 + i * 16 + (lane & 15);
      av[i] = *(const bf16x8*)(As + row * 32 + (lane >> 4) * 8);
    }
#pragma unroll
    for (int j = 0; j < 4; ++j) {
      int col = wc * 64 + j * 16 + (lane & 15);
      bv[j] = *(const bf16x8*)(Bs + col * 32 + (lane >> 4) * 8);
    }
#pragma unroll
    for (int i = 0; i < 4; ++i)
#pragma unroll
      for (int j = 0; j < 4; ++j)
        acc[i][j] = __builtin_amdgcn_mfma_f32_16x16x32_bf16(av[i], bv[j], acc[i][j], 0, 0, 0);
    __syncthreads();
  }

  const int fq = lane >> 4, fr = lane & 15;
#pragma unroll
  for (int i = 0; i < 4; ++i) {
#pragma unroll
    for (int j = 0; j < 4; ++j) {
      int gcol = n0 + wc * 64 + j * 16 + fr;
      float bsum = bias0[gcol];
      if (MODE == 2) bsum += bias1[gcol];
#pragma unroll
      for (int r = 0; r < 4; ++r) {
        int gm = m0 + wr * 64 + i * 16 + fq * 4 + r;
        float v = acc[i][j][r] + bsum;
        if (MODE == 0) {
          ((float*)Cout)[(long)gm * N + gcol] = v;
        } else if (MODE == 1) {
          ((ushort_t*)Cout)[(long)gm * N + gcol] = f2bf(tanhf(v));
        } else {
          int b = gm >> TLB, tl = gm & ((1 << TLB) - 1);
          int wgp = (gcol >> 4) & 63, g = gcol >> 10, u = gcol & 15;
          ((ushort_t*)Cout)[((((long)tl * 64 + wgp) * 64 + b) << 6) + g * 16 + u] = f2bf(v);
        }
      }
    }
  }
}

// ---------------- persistent LSTM scan (one chunk of C=1<<TLB timesteps) ----------------
// R15: FINE-GRAINED producer dependencies replace the global barrier.
// WG p produces h-slice of units [p*16, p*16+16) per step (flag tag tbase+2+tl).
// A consuming wave (K-half g) needs producers [g*32, g*32+32); before loading
// areg slice ksg it checks the 2 producers {2*rot, 2*rot+1} via a 32-lane flag
// gather + ballot, in wg-rotated order. Detection overlaps with earlier slices'
// loads; no wave0 poll, no broadcast, one fewer syncthreads per step. Skew is
// bounded at 1 step by the data dependence (each WG consumes all 64 producers
// per step through its two K-half wave groups). Publish path unchanged.
template <int TLB>
__global__ __launch_bounds__(512, 2) void lstm_scan(const ushort_t* __restrict__ whh,
                                                    const ushort_t* __restrict__ gxc,  // [C][64][NB][64]
                                                    ushort_t* __restrict__ hseq,       // [C+1][NB][NH]
                                                    float* __restrict__ cbuf,          // [NB][NH]
                                                    ushort_t* __restrict__ hs,         // [NB][NTT][NH]
                                                    uint_t* __restrict__ flags,        // [64] @128B stride
                                                    int t0, uint_t tbase) {
  constexpr int C = 1 << TLB;
  extern __shared__ char smem[];
  float* pre = (float*)(smem + 64 * NH * 2);  // [64][64] fp32 (16KB)
  const int wg = blockIdx.x, tid = threadIdx.x;
  const int wave = tid >> 6, lane = tid & 63;
  const int fq = lane >> 4, fr = lane & 15;
  const int g = wave >> 2, w2 = wave & 3;

  // stage weights into fragment-ordered LDS:
  // frag[(ksg*4+nt)*64 + fq*16 + fr] <- W[n=nt*16+fr][k=ksg*32+fq*8 ..+8]
  for (int idx = tid; idx < 64 * 128; idx += 512) {
    int n = idx >> 7, kc = idx & 127;  // kc: 16B chunk (8 bf16) along K
    int grow = (n >> 4) * NH + wg * 16 + (n & 15);
    bf16x8 w = *(const bf16x8*)(whh + (long)grow * NH + kc * 8);
    int frag = ((kc >> 2) * 4 + (n >> 4)) * 64 + (kc & 3) * 16 + (n & 15);
    *(bf16x8*)(smem + frag * 16) = w;
  }
  const int cb = tid >> 3, cup = tid & 7;  // thread owns (b=cb, u=2*cup, 2*cup+1)
  float c0, c1;
  if (t0 == 0) {
    uint_t* p = (uint_t*)(hseq + cb * NH + wg * 16 + cup * 2);
    __hip_atomic_store(p, 0u, __ATOMIC_RELAXED, __HIP_MEMORY_SCOPE_AGENT);
    c0 = 0.f; c1 = 0.f;
  } else {
    c0 = cbuf[cb * NH + wg * 16 + cup * 2];
    c1 = cbuf[cb * NH + wg * 16 + cup * 2 + 1];
  }

  const int bb = w2 * 16;          // batch base for this wave
  const int abrow = bb + fr;       // A-frag row (batch)
  const int lane16 = lane * 16;
  const int flidx = (g * 32 + (lane & 31)) * 32;  // this wave's producer-flag slot
  f32x4 zero = {0.f, 0.f, 0.f, 0.f};

  ushort_t gxr[16];
  auto prefetch = [&](int tl) {  // g==0 waves only: all 64 n for own batches
#pragma unroll
    for (int nt = 0; nt < 4; ++nt)
#pragma unroll
      for (int r = 0; r < 4; ++r)
        gxr[nt * 4 + r] =
            gxc[((((long)tl * 64 + wg) * 64 + (bb + fq * 4 + r)) << 6) + nt * 16 + fr];
  };

  // prologue: drain staging/init stores, publish readiness, invalidate stale lines
  asm volatile("s_waitcnt vmcnt(0)" ::: "memory");
  __syncthreads();
  if (tid == 0)
    __hip_atomic_store(flags + wg * 32, tbase + 1, __ATOMIC_RELAXED, __HIP_MEMORY_SCOPE_AGENT);
  __builtin_amdgcn_fence(__ATOMIC_ACQUIRE, "agent");  // drop stale hseq/gxc lines (per launch)
  if (g == 0) prefetch(0);

  for (int tl = 0; tl < C; ++tl) {
    const ushort_t* hc = hseq + (size_t)tl * (NB * NH);
    const uint_t ctag = tbase + 1 + tl;  // consume tag for slot tl

    // fine-grained dependency: check producers per slice, load as available
    uint_t ready = 0;
    bf16x8 areg[16];
#pragma unroll
    for (int ks = 0; ks < 16; ++ks) {
      int rot = (ks + wg) & 15;
      int ksg = g * 16 + rot;
      uint_t need = 3u << (2 * rot);  // producers {2*rot, 2*rot+1} of this K-half
      while ((ready & need) != need) {
        uint_t v = __hip_atomic_load(flags + flidx, __ATOMIC_RELAXED, __HIP_MEMORY_SCOPE_AGENT);
        ready = (uint_t)__ballot(v >= ctag);
        if ((ready & need) != need) __builtin_amdgcn_s_sleep(1);
      }
      areg[ks] = *(const bf16x8*)(hc + abrow * NH + ksg * 32 + fq * 8);
    }
    __builtin_amdgcn_sched_barrier(0);

    f32x4 acc[4] = {zero, zero, zero, zero};
#pragma unroll
    for (int ks = 0; ks < 16; ++ks) {
      int ksg = g * 16 + ((ks + wg) & 15);
#pragma unroll
      for (int nt = 0; nt < 4; ++nt) {
        bf16x8 w = *(const bf16x8*)(smem + ((ksg * 4 + nt) << 10) + lane16);
        acc[nt] = __builtin_amdgcn_mfma_f32_16x16x32_bf16(areg[ks], w, acc[nt], 0, 0, 0);
      }
    }
    // combine K-half partials via pre[]
    if (g == 1) {
#pragma unroll
      for (int nt = 0; nt < 4; ++nt)
#pragma unroll
        for (int r = 0; r < 4; ++r)
          pre[(bb + fq * 4 + r) * 64 + nt * 16 + fr] = acc[nt][r];
    }
    __syncthreads();  // S1: partials ready
    if (g == 0) {
#pragma unroll
      for (int nt = 0; nt < 4; ++nt)
#pragma unroll
        for (int r = 0; r < 4; ++r) {
          int ii = (bb + fq * 4 + r) * 64 + nt * 16 + fr;
          pre[ii] = pre[ii] + acc[nt][r] + bf2f(gxr[nt * 4 + r]);
        }
    }
    __syncthreads();  // S2: pre complete
    // gates + state update for (cb, u0, u1)
    float h01[2];
#pragma unroll
    for (int k = 0; k < 2; ++k) {
      int u = cup * 2 + k;
      float xi = pre[cb * 64 + 0 * 16 + u];
      float xf = pre[cb * 64 + 1 * 16 + u];
      float xg = pre[cb * 64 + 2 * 16 + u];
      float xo = pre[cb * 64 + 3 * 16 + u];
      float ig = 1.f / (1.f + __expf(-xi));
      float fg = 1.f / (1.f + __expf(-xf));
      float gg = tanh_f(xg);
      float og = 1.f / (1.f + __expf(-xo));
      float& c = k ? c1 : c0;
      c = fg * c + ig * gg;
      h01[k] = og * tanh_f(c);
    }
    uint_t hpack = (uint_t)f2bf(h01[0]) | ((uint_t)f2bf(h01[1]) << 16);
    uint_t* hdst = (uint_t*)(hseq + (size_t)(tl + 1) * (NB * NH) + cb * NH + cup * 2 + wg * 16);
    __hip_atomic_store(hdst, hpack, __ATOMIC_RELAXED, __HIP_MEMORY_SCOPE_AGENT);
    if (tl == C - 1) {  // hand h(final) to next chunk's slot 0
      uint_t* h0 = (uint_t*)(hseq + cb * NH + wg * 16 + cup * 2);
      __hip_atomic_store(h0, hpack, __ATOMIC_RELAXED, __HIP_MEMORY_SCOPE_AGENT);
    }

    // publish: drain h stores (all threads), WG-sync, then flag
    asm volatile("s_waitcnt vmcnt(0)" ::: "memory");
    __syncthreads();  // S3: all h stores of this WG acked at LLC
    if (tid == 0)
      __hip_atomic_store(flags + wg * 32, tbase + 2 + tl, __ATOMIC_RELAXED, __HIP_MEMORY_SCOPE_AGENT);
    // off-critical-path: hs stream + next gx (overlaps next step's polls elsewhere)
    *(uint_t*)(hs + ((size_t)cb * NTT + t0 + tl) * NH + wg * 16 + cup * 2) = hpack;
    if (g == 0 && tl + 1 < C) prefetch(tl + 1);
    // NO trailing barrier: next step's per-slice checks gate consumption
  }
  // persist c for next chunk
  cbuf[cb * NH + wg * 16 + cup * 2] = c0;
  cbuf[cb * NH + wg * 16 + cup * 2 + 1] = c1;
}

// ---------------- host ----------------
extern "C" void kernel_launch(void* const* d_in, const int* in_sizes, int n_in,
                              void* d_out, int out_size, void* d_ws, size_t ws_size,
                              hipStream_t stream) {
  const float* x = (const float*)d_in[0];
  const float* w1 = (const float*)d_in[1];
  const float* b1 = (const float*)d_in[2];
  const float* w_ih = (const float*)d_in[3];
  const float* w_hh = (const float*)d_in[4];
  const float* b_ih = (const float*)d_in[5];
  const float* b_hh = (const float*)d_in[6];
  const float* w3 = (const float*)d_in[7];
  const float* b3 = (const float*)d_in[8];

  char* ws = (char*)d_ws;
  size_t off = 0;
  auto alloc = [&](size_t bytes) {
    char* p = ws + off;
    off += (bytes + 255) & ~(size_t)255;
    return p;
  };
  ushort_t* w1b = (ushort_t*)alloc(sizeof(ushort_t) * NH * NI);
  ushort_t* wihb = (ushort_t*)alloc(sizeof(ushort_t) * NG * NH);
  ushort_t* whhb = (ushort_t*)alloc(sizeof(ushort_t) * NG * NH);
  ushort_t* w3b = (ushort_t*)alloc(sizeof(ushort_t) * NA * NH);
  ushort_t* fb = (ushort_t*)alloc(sizeof(ushort_t) * (size_t)NB * NTT * NH);  // f, then hs (in-place)
  float* cbuf = (float*)alloc(sizeof(float) * NB * NH);
  uint_t* flags = (uint_t*)alloc(sizeof(uint_t) * 64 * 32);
  size_t off_small = off;
  // optional big-chunk gx buffer (C=128): 67MB in ws
  ushort_t* gxc_big = (ushort_t*)alloc(sizeof(ushort_t) * (size_t)128 * 64 * NB * 64);
  bool big = (off <= ws_size);
  if (!big && off_small > ws_size) {
    hipMemsetAsync(d_out, 0xFF, 256, stream);  // NaN sentinel: ws too small even for base
    return;
  }

  // scratch carved out of d_out (dead before fc3 writes d_out):
  ushort_t* xb = (ushort_t*)d_out;                           // bf16 x for fc1 (33.5MB)
  ushort_t* hseq = (ushort_t*)d_out;                         // [C+1][NB][NH] (reuses xb)
  ushort_t* gxc_small = (ushort_t*)d_out + (size_t)NB * NTT * NI;  // C=64 gx (33.5MB)

  auto cast = [&](const float* src, ushort_t* dst, int n) {
    cast_f32_bf16<<<dim3((n / 4 + 255) / 256), dim3(256), 0, stream>>>(src, dst, n);
  };
  cast(x, xb, NB * NTT * NI);
  cast(w1, w1b, NH * NI);
  cast(w_ih, wihb, NG * NH);
  cast(w_hh, whhb, NG * NH);
  cast(w3, w3b, NA * NH);

  // fc1 + tanh -> f (bf16)
  gemm_nt<1, 6><<<dim3(NH / 128, NB * NTT / 128), dim3(256), 0, stream>>>(
      (const short*)xb, (const short*)w1b, b1, nullptr, fb, NB * NTT, NH, NI, 0);

  hipMemsetAsync(flags, 0, sizeof(uint_t) * 64 * 32, stream);
  int ldsz = 64 * NH * 2 + 64 * 64 * 4;
  hipFuncSetAttribute(reinterpret_cast<const void*>(&lstm_scan<6>),
                      hipFuncAttributeMaxDynamicSharedMemorySize, ldsz);
  hipFuncSetAttribute(reinterpret_cast<const void*>(&lstm_scan<7>),
                      hipFuncAttributeMaxDynamicSharedMemorySize, ldsz);

  if (big) {
    // C = 128: 4 chunks, gxc in ws
    for (int chunk = 0; chunk < NTT / 128; ++chunk) {
      int t0 = chunk * 128;
      gemm_nt<2, 7><<<dim3(NG / 128, NB * 128 / 128), dim3(256), 0, stream>>>(
          (const short*)fb, (const short*)wihb, b_ih, b_hh, gxc_big, NB * 128, NG, NH, t0);
      lstm_scan<7><<<dim3(64), dim3(512), ldsz, stream>>>(
          whhb, gxc_big, hseq, cbuf, fb, flags, t0, (uint_t)(chunk * 129));
    }
  } else {
    // C = 64: 8 chunks, gxc in d_out (proven fallback)
    for (int chunk = 0; chunk < NTT / 64; ++chunk) {
      int t0 = chunk * 64;
      gemm_nt<2, 6><<<dim3(NG / 128, NB * 64 / 128), dim3(256), 0, stream>>>(
          (const short*)fb, (const short*)wihb, b_ih, b_hh, gxc_small, NB * 64, NG, NH, t0);
      lstm_scan<6><<<dim3(64), dim3(512), ldsz, stream>>>(
          whhb, gxc_small, hseq, cbuf, fb, flags, t0, (uint_t)(chunk * 65));
    }
  }

  // fc3 head -> d_out (fp32)
  gemm_nt<0, 6><<<dim3(NA / 128, NB * NTT / 128), dim3(256), 0, stream>>>(
      (const short*)fb, (const short*)w3b, b3, nullptr, d_out, NB * NTT, NA, NH, 0);
}

// Round 16
// 3549.580 us; speedup vs baseline: 1.1327x; 1.1327x over previous
//
#include <hip/hip_runtime.h>
#include <cstdint>
#include <cstddef>

#define DEVI __device__ __forceinline__

typedef __attribute__((ext_vector_type(8))) short bf16x8;
typedef __attribute__((ext_vector_type(4))) float f32x4;
typedef unsigned short ushort_t;
typedef unsigned int uint_t;

// problem dims (fixed)
constexpr int NB = 64;    // batch
constexpr int NTT = 512;  // seq len
constexpr int NI = 512;   // input feat
constexpr int NH = 1024;  // hidden
constexpr int NA = 512;   // out feat
constexpr int NG = 4096;  // 4*NH
constexpr int C64 = 64;   // scan chunk

DEVI float bf2f(ushort_t u) { union { uint_t i; float f; } v; v.i = ((uint_t)u) << 16; return v.f; }
DEVI ushort_t f2bf(float f) {
  union { float f; uint_t i; } v; v.f = f;
  uint_t x = v.i;
  return (ushort_t)((x + 0x7fffu + ((x >> 16) & 1u)) >> 16);
}

// clamped fast tanh: safe for |x| large (clamp before exp), bf16-accurate
DEVI float tanh_f(float x) {
  x = fminf(fmaxf(x, -15.f), 15.f);
  float e = __expf(2.f * x);
  return (e - 1.f) / (e + 1.f);
}

DEVI void gload_lds16(const void* g, void* l) {
  __builtin_amdgcn_global_load_lds((__attribute__((address_space(1))) void*)g,
                                   (__attribute__((address_space(3))) void*)l, 16, 0, 0);
}

// ---------------- cast fp32 -> bf16 ----------------
__global__ __launch_bounds__(256) void cast_f32_bf16(const float* __restrict__ in,
                                                     ushort_t* __restrict__ out, int n) {
  int i = (blockIdx.x * 256 + threadIdx.x) * 4;
  if (i >= n) return;
  float4 v = *(const float4*)(in + i);
  ushort4 o;
  o.x = f2bf(v.x); o.y = f2bf(v.y); o.z = f2bf(v.z); o.w = f2bf(v.w);
  *(ushort4*)(out + i) = o;
}

// ---------------- generic NT GEMM (256 thr): C[M,N] = A[M,K] * B[N,K]^T ----------------
// MODE 0: fp32 out, +bias0 (fc3) | MODE 1: bf16 out, tanh (fc1) |
// MODE 2: chunked gx (chunk = 1<<TLB steps): scatter to gxc[tl][wg][b][g*16+u]
template <int MODE, int TLB>
__global__ __launch_bounds__(256) void gemm_nt(const short* __restrict__ A,
                                               const short* __restrict__ Bm,
                                               const float* __restrict__ bias0,
                                               const float* __restrict__ bias1,
                                               void* __restrict__ Cout,
                                               int M, int N, int K, int t0) {
  __shared__ short As[128 * 32];
  __shared__ short Bs[128 * 32];
  const int tid = threadIdx.x;
  const int wave = tid >> 6, lane = tid & 63;
  const int m0 = blockIdx.y * 128, n0 = blockIdx.x * 128;
  const int wr = wave >> 1, wc = wave & 1;

  f32x4 zero = {0.f, 0.f, 0.f, 0.f};
  f32x4 acc[4][4];
#pragma unroll
  for (int i = 0; i < 4; ++i)
#pragma unroll
    for (int j = 0; j < 4; ++j) acc[i][j] = zero;

  const int lrow = lane >> 2;
  const int lk = (lane & 3) * 8;

  for (int kt = 0; kt < K; kt += 32) {
#pragma unroll
    for (int c = 0; c < 2; ++c) {
      int q = wave + 4 * c;
      int row = m0 + q * 16 + lrow;
      long arow = (MODE == 2) ? ((long)(row >> TLB) * NTT + t0 + (row & ((1 << TLB) - 1)))
                              : (long)row;
      gload_lds16(A + arow * K + kt + lk, As + q * 512);
      gload_lds16(Bm + (long)(n0 + q * 16 + lrow) * K + kt + lk, Bs + q * 512);
    }
    __syncthreads();

    bf16x8 av[4], bv[4];
#pragma unroll
    for (int i = 0; i < 4; ++i) {
      int row = wr * 64 + i * 16 + (lane & 15);
      av[i] = *(const bf16x8*)(As + row * 32 + (lane >> 4) * 8);
    }
#pragma unroll
    for (int j = 0; j < 4; ++j) {
      int col = wc * 64 + j * 16 + (lane & 15);
      bv[j] = *(const bf16x8*)(Bs + col * 32 + (lane >> 4) * 8);
    }
#pragma unroll
    for (int i = 0; i < 4; ++i)
#pragma unroll
      for (int j = 0; j < 4; ++j)
        acc[i][j] = __builtin_amdgcn_mfma_f32_16x16x32_bf16(av[i], bv[j], acc[i][j], 0, 0, 0);
    __syncthreads();
  }

  const int fq = lane >> 4, fr = lane & 15;
#pragma unroll
  for (int i = 0; i < 4; ++i) {
#pragma unroll
    for (int j = 0; j < 4; ++j) {
      int gcol = n0 + wc * 64 + j * 16 + fr;
      float bsum = bias0[gcol];
      if (MODE == 2) bsum += bias1[gcol];
#pragma unroll
      for (int r = 0; r < 4; ++r) {
        int gm = m0 + wr * 64 + i * 16 + fq * 4 + r;
        float v = acc[i][j][r] + bsum;
        if (MODE == 0) {
          ((float*)Cout)[(long)gm * N + gcol] = v;
        } else if (MODE == 1) {
          ((ushort_t*)Cout)[(long)gm * N + gcol] = f2bf(tanhf(v));
        } else {
          int b = gm >> TLB, tl = gm & ((1 << TLB) - 1);
          int wgp = (gcol >> 4) & 63, g = gcol >> 10, u = gcol & 15;
          ((ushort_t*)Cout)[((((long)tl * 64 + wgp) * 64 + b) << 6) + g * 16 + u] = f2bf(v);
        }
      }
    }
  }
}

// ---------------- FUSED: scan chunk k (blocks 0-63) + gx GEMM chunk k+1 (blocks 64+) ----
// Scan body = R7/R14 structure verbatim (proven 6.5 us/step floor). GEMM for the
// NEXT chunk depends only on f (rows t0+64..), runs on the ~192 idle CUs and
// hides under the 419 us scan. No cross-dependency inside the kernel.
__global__ __launch_bounds__(512, 2) void scan_fused(const ushort_t* __restrict__ whh,
                                                     const ushort_t* __restrict__ gxc,  // [64][64][NB][64] chunk k
                                                     const short* __restrict__ fsrc,    // f [B,T,H] bf16
                                                     const ushort_t* __restrict__ wihb,
                                                     const float* __restrict__ b_ih,
                                                     const float* __restrict__ b_hh,
                                                     ushort_t* __restrict__ gxn,        // chunk k+1 out
                                                     ushort_t* __restrict__ hseq,       // [65][NB][NH]
                                                     float* __restrict__ cbuf,          // [NB][NH]
                                                     ushort_t* __restrict__ hs,         // [NB][NTT][NH]
                                                     uint_t* __restrict__ flags,
                                                     int t0, uint_t tbase, int do_next) {
  extern __shared__ char smem[];
  const int tid = threadIdx.x;
  const int wave = tid >> 6, lane = tid & 63;
  const int fq = lane >> 4, fr = lane & 15;

  if (blockIdx.x >= 64) {
    // ================= gx GEMM for chunk k+1 (512 threads, 128x128 tile) ==========
    if (!do_next) return;
    const int idx = blockIdx.x - 64;
    const int m0 = (idx >> 5) * 128;  // M = NB*64 = 4096 -> 32 m-tiles
    const int n0 = (idx & 31) * 128;  // N = 4096 -> 32 n-tiles
    const int wr = wave >> 1, wc = wave & 1;  // 4x2 waves over 128x128
    short* As = (short*)smem;
    short* Bs = (short*)smem + 128 * 32;
    f32x4 zero = {0.f, 0.f, 0.f, 0.f};
    f32x4 acc[2][4];
#pragma unroll
    for (int i = 0; i < 2; ++i)
#pragma unroll
      for (int j = 0; j < 4; ++j) acc[i][j] = zero;
    const int lrow = lane >> 2, lk = (lane & 3) * 8;
    const int t1 = t0 + C64;

    for (int kt = 0; kt < NH; kt += 32) {
      {  // wave q stages As chunk q and Bs chunk q (16 rows x 32 cols each)
        int row = m0 + wave * 16 + lrow;
        long arow = (long)(row >> 6) * NTT + t1 + (row & 63);
        gload_lds16(fsrc + arow * NH + kt + lk, As + wave * 512);
        gload_lds16(wihb + (long)(n0 + wave * 16 + lrow) * NH + kt + lk, Bs + wave * 512);
      }
      __syncthreads();
      bf16x8 av[2], bv[4];
#pragma unroll
      for (int i = 0; i < 2; ++i) {
        int row = wr * 32 + i * 16 + (lane & 15);
        av[i] = *(const bf16x8*)(As + row * 32 + (lane >> 4) * 8);
      }
#pragma unroll
      for (int j = 0; j < 4; ++j) {
        int col = wc * 64 + j * 16 + (lane & 15);
        bv[j] = *(const bf16x8*)(Bs + col * 32 + (lane >> 4) * 8);
      }
#pragma unroll
      for (int i = 0; i < 2; ++i)
#pragma unroll
        for (int j = 0; j < 4; ++j)
          acc[i][j] = __builtin_amdgcn_mfma_f32_16x16x32_bf16(av[i], bv[j], acc[i][j], 0, 0, 0);
      __syncthreads();
    }
#pragma unroll
    for (int i = 0; i < 2; ++i) {
#pragma unroll
      for (int j = 0; j < 4; ++j) {
        int gcol = n0 + wc * 64 + j * 16 + fr;
        float bsum = b_ih[gcol] + b_hh[gcol];
        int wgp = (gcol >> 4) & 63, gg = gcol >> 10, u = gcol & 15;
#pragma unroll
        for (int r = 0; r < 4; ++r) {
          int gm = m0 + wr * 32 + i * 16 + fq * 4 + r;
          int b = gm >> 6, tl = gm & 63;
          gxn[((((long)tl * 64 + wgp) * 64 + b) << 6) + gg * 16 + u] = f2bf(acc[i][j][r] + bsum);
        }
      }
    }
    return;
  }

  // ================= scan (R14 structure verbatim, C=64) =================
  float* pre = (float*)(smem + 64 * NH * 2);  // [64][64] fp32
  const int wg = blockIdx.x;
  const int g = wave >> 2, w2 = wave & 3;

  for (int idx = tid; idx < 64 * 128; idx += 512) {
    int n = idx >> 7, kc = idx & 127;
    int grow = (n >> 4) * NH + wg * 16 + (n & 15);
    bf16x8 w = *(const bf16x8*)(whh + (long)grow * NH + kc * 8);
    int frag = ((kc >> 2) * 4 + (n >> 4)) * 64 + (kc & 3) * 16 + (n & 15);
    *(bf16x8*)(smem + frag * 16) = w;
  }
  const int cb = tid >> 3, cup = tid & 7;
  float c0, c1;
  if (t0 == 0) {
    uint_t* p = (uint_t*)(hseq + cb * NH + wg * 16 + cup * 2);
    __hip_atomic_store(p, 0u, __ATOMIC_RELAXED, __HIP_MEMORY_SCOPE_AGENT);
    c0 = 0.f; c1 = 0.f;
  } else {
    c0 = cbuf[cb * NH + wg * 16 + cup * 2];
    c1 = cbuf[cb * NH + wg * 16 + cup * 2 + 1];
  }

  const int bb = w2 * 16;
  const int abrow = bb + fr;
  const int lane16 = lane * 16;
  f32x4 zero = {0.f, 0.f, 0.f, 0.f};

  ushort_t gxr[16];
  auto prefetch = [&](int tl) {
#pragma unroll
    for (int nt = 0; nt < 4; ++nt)
#pragma unroll
      for (int r = 0; r < 4; ++r)
        gxr[nt * 4 + r] =
            gxc[((((long)tl * 64 + wg) * 64 + (bb + fq * 4 + r)) << 6) + nt * 16 + fr];
  };
  auto poll = [&](uint_t t) {
    if (tid < 64) {
      uint_t* fp = flags + tid * 32;
      for (;;) {
        uint_t v = __hip_atomic_load(fp, __ATOMIC_RELAXED, __HIP_MEMORY_SCOPE_AGENT);
        if (__all(v >= t)) break;
        __builtin_amdgcn_s_sleep(1);
      }
    }
  };

  asm volatile("s_waitcnt vmcnt(0)" ::: "memory");
  __syncthreads();
  if (tid == 0)
    __hip_atomic_store(flags + wg * 32, tbase + 1, __ATOMIC_RELAXED, __HIP_MEMORY_SCOPE_AGENT);
  poll(tbase + 1);
  __builtin_amdgcn_fence(__ATOMIC_ACQUIRE, "agent");
  __syncthreads();
  if (g == 0) prefetch(0);

  for (int tl = 0; tl < C64; ++tl) {
    const ushort_t* hc = hseq + (size_t)tl * (NB * NH);
    bf16x8 areg[16];
#pragma unroll
    for (int ks = 0; ks < 16; ++ks) {
      int ksg = g * 16 + ((ks + wg) & 15);
      areg[ks] = *(const bf16x8*)(hc + abrow * NH + ksg * 32 + fq * 8);
    }
    __builtin_amdgcn_sched_barrier(0);

    f32x4 acc[4] = {zero, zero, zero, zero};
#pragma unroll
    for (int ks = 0; ks < 16; ++ks) {
      int ksg = g * 16 + ((ks + wg) & 15);
#pragma unroll
      for (int nt = 0; nt < 4; ++nt) {
        bf16x8 w = *(const bf16x8*)(smem + ((ksg * 4 + nt) << 10) + lane16);
        acc[nt] = __builtin_amdgcn_mfma_f32_16x16x32_bf16(areg[ks], w, acc[nt], 0, 0, 0);
      }
    }
    if (g == 1) {
#pragma unroll
      for (int nt = 0; nt < 4; ++nt)
#pragma unroll
        for (int r = 0; r < 4; ++r)
          pre[(bb + fq * 4 + r) * 64 + nt * 16 + fr] = acc[nt][r];
    }
    __syncthreads();
    if (g == 0) {
#pragma unroll
      for (int nt = 0; nt < 4; ++nt)
#pragma unroll
        for (int r = 0; r < 4; ++r) {
          int ii = (bb + fq * 4 + r) * 64 + nt * 16 + fr;
          pre[ii] = pre[ii] + acc[nt][r] + bf2f(gxr[nt * 4 + r]);
        }
    }
    __syncthreads();
    float h01[2];
#pragma unroll
    for (int k = 0; k < 2; ++k) {
      int u = cup * 2 + k;
      float xi = pre[cb * 64 + 0 * 16 + u];
      float xf = pre[cb * 64 + 1 * 16 + u];
      float xg = pre[cb * 64 + 2 * 16 + u];
      float xo = pre[cb * 64 + 3 * 16 + u];
      float ig = 1.f / (1.f + __expf(-xi));
      float fg = 1.f / (1.f + __expf(-xf));
      float gg = tanh_f(xg);
      float og = 1.f / (1.f + __expf(-xo));
      float& c = k ? c1 : c0;
      c = fg * c + ig * gg;
      h01[k] = og * tanh_f(c);
    }
    uint_t hpack = (uint_t)f2bf(h01[0]) | ((uint_t)f2bf(h01[1]) << 16);
    uint_t* hdst = (uint_t*)(hseq + (size_t)(tl + 1) * (NB * NH) + cb * NH + wg * 16 + cup * 2);
    __hip_atomic_store(hdst, hpack, __ATOMIC_RELAXED, __HIP_MEMORY_SCOPE_AGENT);
    if (tl == C64 - 1) {
      uint_t* h0 = (uint_t*)(hseq + cb * NH + wg * 16 + cup * 2);
      __hip_atomic_store(h0, hpack, __ATOMIC_RELAXED, __HIP_MEMORY_SCOPE_AGENT);
    }

    asm volatile("s_waitcnt vmcnt(0)" ::: "memory");
    __syncthreads();
    uint_t t = tbase + 2 + tl;
    if (tid == 0)
      __hip_atomic_store(flags + wg * 32, t, __ATOMIC_RELAXED, __HIP_MEMORY_SCOPE_AGENT);
    *(uint_t*)(hs + ((size_t)cb * NTT + t0 + tl) * NH + wg * 16 + cup * 2) = hpack;
    if (g == 0 && tl + 1 < C64) prefetch(tl + 1);
    poll(t);
    __syncthreads();
    asm volatile("" ::: "memory");
  }
  cbuf[cb * NH + wg * 16 + cup * 2] = c0;
  cbuf[cb * NH + wg * 16 + cup * 2 + 1] = c1;
}

// ---------------- host ----------------
extern "C" void kernel_launch(void* const* d_in, const int* in_sizes, int n_in,
                              void* d_out, int out_size, void* d_ws, size_t ws_size,
                              hipStream_t stream) {
  const float* x = (const float*)d_in[0];
  const float* w1 = (const float*)d_in[1];
  const float* b1 = (const float*)d_in[2];
  const float* w_ih = (const float*)d_in[3];
  const float* w_hh = (const float*)d_in[4];
  const float* b_ih = (const float*)d_in[5];
  const float* b_hh = (const float*)d_in[6];
  const float* w3 = (const float*)d_in[7];
  const float* b3 = (const float*)d_in[8];

  char* ws = (char*)d_ws;
  size_t off = 0;
  auto alloc = [&](size_t bytes) {
    char* p = ws + off;
    off += (bytes + 255) & ~(size_t)255;
    return p;
  };
  ushort_t* w1b = (ushort_t*)alloc(sizeof(ushort_t) * NH * NI);
  ushort_t* wihb = (ushort_t*)alloc(sizeof(ushort_t) * NG * NH);
  ushort_t* whhb = (ushort_t*)alloc(sizeof(ushort_t) * NG * NH);
  ushort_t* w3b = (ushort_t*)alloc(sizeof(ushort_t) * NA * NH);
  ushort_t* fb = (ushort_t*)alloc(sizeof(ushort_t) * (size_t)NB * NTT * NH);  // f, then hs (in-place)
  float* cbuf = (float*)alloc(sizeof(float) * NB * NH);
  uint_t* flags = (uint_t*)alloc(sizeof(uint_t) * 64 * 32);
  size_t off_small = off;
  // double-buffered gx (C=64): 2 x 33.55 MB in ws -> same total as proven R14 big path
  ushort_t* gxcA = (ushort_t*)alloc(sizeof(ushort_t) * (size_t)C64 * 64 * NB * 64);
  ushort_t* gxcB = (ushort_t*)alloc(sizeof(ushort_t) * (size_t)C64 * 64 * NB * 64);
  bool fused_ok = (off <= ws_size);
  if (!fused_ok && off_small > ws_size) {
    hipMemsetAsync(d_out, 0xFF, 256, stream);  // NaN sentinel: ws too small even for base
    return;
  }

  // scratch carved out of d_out (dead before fc3 writes d_out):
  ushort_t* xb = (ushort_t*)d_out;                           // bf16 x for fc1 (33.5MB)
  ushort_t* hseq = (ushort_t*)d_out;                         // [65][NB][NH] (reuses xb)
  ushort_t* gxc_small = (ushort_t*)d_out + (size_t)NB * NTT * NI;  // fallback gx (33.5MB)

  auto cast = [&](const float* src, ushort_t* dst, int n) {
    cast_f32_bf16<<<dim3((n / 4 + 255) / 256), dim3(256), 0, stream>>>(src, dst, n);
  };
  cast(x, xb, NB * NTT * NI);
  cast(w1, w1b, NH * NI);
  cast(w_ih, wihb, NG * NH);
  cast(w_hh, whhb, NG * NH);
  cast(w3, w3b, NA * NH);

  // fc1 + tanh -> f (bf16)
  gemm_nt<1, 6><<<dim3(NH / 128, NB * NTT / 128), dim3(256), 0, stream>>>(
      (const short*)xb, (const short*)w1b, b1, nullptr, fb, NB * NTT, NH, NI, 0);

  hipMemsetAsync(flags, 0, sizeof(uint_t) * 64 * 32, stream);
  int ldsz = 64 * NH * 2 + 64 * 64 * 4;  // 144 KB
  hipFuncSetAttribute(reinterpret_cast<const void*>(&scan_fused),
                      hipFuncAttributeMaxDynamicSharedMemorySize, ldsz);

  if (fused_ok) {
    // gx for chunk 0 standalone; chunks 1..7 produced inside the fused scans
    gemm_nt<2, 6><<<dim3(NG / 128, NB * C64 / 128), dim3(256), 0, stream>>>(
        (const short*)fb, (const short*)wihb, b_ih, b_hh, gxcA, NB * C64, NG, NH, 0);
    for (int chunk = 0; chunk < NTT / C64; ++chunk) {
      int t0 = chunk * C64;
      ushort_t* cur = (chunk & 1) ? gxcB : gxcA;
      ushort_t* nxt = (chunk & 1) ? gxcA : gxcB;
      int do_next = (chunk + 1 < NTT / C64) ? 1 : 0;
      int nblocks = do_next ? (64 + 1024) : 64;
      scan_fused<<<dim3(nblocks), dim3(512), ldsz, stream>>>(
          whhb, cur, (const short*)fb, wihb, b_ih, b_hh, nxt,
          hseq, cbuf, fb, flags, t0, (uint_t)(chunk * 65), do_next);
    }
  } else {
    // fallback: proven non-fused C=64 path, gx in d_out
    for (int chunk = 0; chunk < NTT / C64; ++chunk) {
      int t0 = chunk * C64;
      gemm_nt<2, 6><<<dim3(NG / 128, NB * C64 / 128), dim3(256), 0, stream>>>(
          (const short*)fb, (const short*)wihb, b_ih, b_hh, gxc_small, NB * C64, NG, NH, t0);
      scan_fused<<<dim3(64), dim3(512), ldsz, stream>>>(
          whhb, gxc_small, (const short*)fb, wihb, b_ih, b_hh, gxc_small,
          hseq, cbuf, fb, flags, t0, (uint_t)(chunk * 65), 0);
    }
  }

  // fc3 head -> d_out (fp32)
  gemm_nt<0, 6><<<dim3(NA / 128, NB * NTT / 128), dim3(256), 0, stream>>>(
      (const short*)fb, (const short*)w3b, b3, nullptr, d_out, NB * NTT, NA, NH, 0);
}

// Round 17
// 3521.646 us; speedup vs baseline: 1.1417x; 1.0079x over previous
//
#include <hip/hip_runtime.h>
#include <cstdint>
#include <cstddef>

#define DEVI __device__ __forceinline__

typedef __attribute__((ext_vector_type(8))) short bf16x8;
typedef __attribute__((ext_vector_type(4))) float f32x4;
typedef unsigned short ushort_t;
typedef unsigned int uint_t;

// problem dims (fixed)
constexpr int NB = 64;    // batch
constexpr int NTT = 512;  // seq len
constexpr int NI = 512;   // input feat
constexpr int NH = 1024;  // hidden
constexpr int NA = 512;   // out feat
constexpr int NG = 4096;  // 4*NH
constexpr int C64 = 64;   // scan chunk

DEVI float bf2f(ushort_t u) { union { uint_t i; float f; } v; v.i = ((uint_t)u) << 16; return v.f; }
DEVI ushort_t f2bf(float f) {
  union { float f; uint_t i; } v; v.f = f;
  uint_t x = v.i;
  return (ushort_t)((x + 0x7fffu + ((x >> 16) & 1u)) >> 16);
}

// clamped fast tanh: safe for |x| large (clamp before exp), bf16-accurate
DEVI float tanh_f(float x) {
  x = fminf(fmaxf(x, -15.f), 15.f);
  float e = __expf(2.f * x);
  return (e - 1.f) / (e + 1.f);
}

DEVI void gload_lds16(const void* g, void* l) {
  __builtin_amdgcn_global_load_lds((__attribute__((address_space(1))) void*)g,
                                   (__attribute__((address_space(3))) void*)l, 16, 0, 0);
}

// ---------------- cast fp32 -> bf16 ----------------
__global__ __launch_bounds__(256) void cast_f32_bf16(const float* __restrict__ in,
                                                     ushort_t* __restrict__ out, int n) {
  int i = (blockIdx.x * 256 + threadIdx.x) * 4;
  if (i >= n) return;
  float4 v = *(const float4*)(in + i);
  ushort4 o;
  o.x = f2bf(v.x); o.y = f2bf(v.y); o.z = f2bf(v.z); o.w = f2bf(v.w);
  *(ushort4*)(out + i) = o;
}

// ---------------- shared GEMM body (256 threads, 128x128 tile) ----------------
// MODE 0: fp32 out, +bias0 (fc3) | MODE 1: bf16 out, tanh (fc1) |
// MODE 2: chunked gx (chunk = 1<<TLB steps): A-row remap, scatter to gxc layout
template <int MODE, int TLB>
DEVI void gemm_body(short* As, short* Bs, const short* __restrict__ A,
                    const short* __restrict__ Bm, const float* __restrict__ bias0,
                    const float* __restrict__ bias1, void* __restrict__ Cout,
                    int N, int K, int t0, int m0, int n0) {
  const int tid = threadIdx.x;
  const int wave = tid >> 6, lane = tid & 63;
  const int wr = wave >> 1, wc = wave & 1;

  f32x4 zero = {0.f, 0.f, 0.f, 0.f};
  f32x4 acc[4][4];
#pragma unroll
  for (int i = 0; i < 4; ++i)
#pragma unroll
    for (int j = 0; j < 4; ++j) acc[i][j] = zero;

  const int lrow = lane >> 2;
  const int lk = (lane & 3) * 8;

  for (int kt = 0; kt < K; kt += 32) {
#pragma unroll
    for (int c = 0; c < 2; ++c) {
      int q = wave + 4 * c;
      int row = m0 + q * 16 + lrow;
      long arow = (MODE == 2) ? ((long)(row >> TLB) * NTT + t0 + (row & ((1 << TLB) - 1)))
                              : (long)row;
      gload_lds16(A + arow * K + kt + lk, As + q * 512);
      gload_lds16(Bm + (long)(n0 + q * 16 + lrow) * K + kt + lk, Bs + q * 512);
    }
    __syncthreads();

    bf16x8 av[4], bv[4];
#pragma unroll
    for (int i = 0; i < 4; ++i) {
      int row = wr * 64 + i * 16 + (lane & 15);
      av[i] = *(const bf16x8*)(As + row * 32 + (lane >> 4) * 8);
    }
#pragma unroll
    for (int j = 0; j < 4; ++j) {
      int col = wc * 64 + j * 16 + (lane & 15);
      bv[j] = *(const bf16x8*)(Bs + col * 32 + (lane >> 4) * 8);
    }
#pragma unroll
    for (int i = 0; i < 4; ++i)
#pragma unroll
      for (int j = 0; j < 4; ++j)
        acc[i][j] = __builtin_amdgcn_mfma_f32_16x16x32_bf16(av[i], bv[j], acc[i][j], 0, 0, 0);
    __syncthreads();
  }

  const int fq = lane >> 4, fr = lane & 15;
#pragma unroll
  for (int i = 0; i < 4; ++i) {
#pragma unroll
    for (int j = 0; j < 4; ++j) {
      int gcol = n0 + wc * 64 + j * 16 + fr;
      float bsum = bias0[gcol];
      if (MODE == 2) bsum += bias1[gcol];
#pragma unroll
      for (int r = 0; r < 4; ++r) {
        int gm = m0 + wr * 64 + i * 16 + fq * 4 + r;
        float v = acc[i][j][r] + bsum;
        if (MODE == 0) {
          ((float*)Cout)[(long)gm * N + gcol] = v;
        } else if (MODE == 1) {
          ((ushort_t*)Cout)[(long)gm * N + gcol] = f2bf(tanhf(v));
        } else {
          int b = gm >> TLB, tl = gm & ((1 << TLB) - 1);
          int wgp = (gcol >> 4) & 63, g = gcol >> 10, u = gcol & 15;
          ((ushort_t*)Cout)[((((long)tl * 64 + wgp) * 64 + b) << 6) + g * 16 + u] = f2bf(v);
        }
      }
    }
  }
}

// generic launcher: m0 = (blockIdx.y * mm + ma) * 128
template <int MODE, int TLB>
__global__ __launch_bounds__(256) void gemm_nt(const short* __restrict__ A,
                                               const short* __restrict__ Bm,
                                               const float* __restrict__ bias0,
                                               const float* __restrict__ bias1,
                                               void* __restrict__ Cout,
                                               int N, int K, int t0, int mm, int ma) {
  __shared__ short As[128 * 32];
  __shared__ short Bs[128 * 32];
  gemm_body<MODE, TLB>(As, Bs, A, Bm, bias0, bias1, Cout, N, K, t0,
                       (blockIdx.y * mm + ma) * 128, blockIdx.x * 128);
}

// ---------------- fused prologue: fc1 rows t>=128 (blocks 0-1535) || gx chunk 0 (1536+) ----
// gx0 reads f rows t<64 written by the prior fc1-part1 kernel; fc1-part2 writes t>=128.
__global__ __launch_bounds__(256) void fused_pre(const short* __restrict__ xb,
                                                 const short* __restrict__ w1b,
                                                 const float* __restrict__ b1,
                                                 ushort_t* __restrict__ fb,
                                                 const short* __restrict__ wihb,
                                                 const float* __restrict__ b_ih,
                                                 const float* __restrict__ b_hh,
                                                 ushort_t* __restrict__ gx0) {
  __shared__ short As[128 * 32];
  __shared__ short Bs[128 * 32];
  if (blockIdx.x < 1536) {  // fc1 part2: m-tiles (b, tq=1..3)
    int lin = blockIdx.x;
    int mt2 = lin >> 3;                     // 0..191
    int b = mt2 / 3, tq = 1 + mt2 % 3;
    gemm_body<1, 6>(As, Bs, xb, w1b, b1, nullptr, fb, NH, NI, 0,
                    (b * 4 + tq) * 128, (lin & 7) * 128);
  } else {  // gx chunk 0
    int idx = blockIdx.x - 1536;            // 0..1023
    gemm_body<2, 6>(As, Bs, (const short*)fb, wihb, b_ih, b_hh, gx0, NG, NH, 0,
                    (idx >> 5) * 128, (idx & 31) * 128);
  }
}

// ---------------- FUSED: scan chunk k (0-63) + gx k+1 (64-1087) + fc3 k-2..k-1 (1088-1343) --
// Scan body = R7/R14/R16 verbatim (proven 6.5 us/step floor). gx for the NEXT
// chunk and fc3 for rows finished two chunks ago run on idle CUs, fully hidden.
__global__ __launch_bounds__(512, 2) void scan_fused(const ushort_t* __restrict__ whh,
                                                     const ushort_t* __restrict__ gxc,
                                                     const short* __restrict__ fsrc,
                                                     const ushort_t* __restrict__ wihb,
                                                     const float* __restrict__ b_ih,
                                                     const float* __restrict__ b_hh,
                                                     ushort_t* __restrict__ gxn,
                                                     const ushort_t* __restrict__ w3b,
                                                     const float* __restrict__ b3,
                                                     float* __restrict__ fc3out,
                                                     ushort_t* __restrict__ hseq,
                                                     float* __restrict__ cbuf,
                                                     ushort_t* __restrict__ hs,
                                                     uint_t* __restrict__ flags,
                                                     int t0, uint_t tbase,
                                                     int do_next, int do_fc3) {
  extern __shared__ char smem[];
  const int tid = threadIdx.x;
  const int wave = tid >> 6, lane = tid & 63;
  const int fq = lane >> 4, fr = lane & 15;

  if (blockIdx.x >= 1088) {
    // ============ fc3 for t in [t0-128, t0) (512 thr, 128x128 tile, fp32 out) ==========
    if (!do_fc3) return;
    const int idx3 = blockIdx.x - 1088;     // 0..255
    const int tq3 = (t0 >> 7) - 1;          // k=2->0, k=4->1, k=6->2
    const int m0 = ((idx3 >> 2) * 4 + tq3) * 128;
    const int n0 = (idx3 & 3) * 128;
    const int wr = wave >> 1, wc = wave & 1;
    short* As = (short*)smem;
    short* Bs = (short*)smem + 128 * 32;
    f32x4 zero = {0.f, 0.f, 0.f, 0.f};
    f32x4 acc[2][4];
#pragma unroll
    for (int i = 0; i < 2; ++i)
#pragma unroll
      for (int j = 0; j < 4; ++j) acc[i][j] = zero;
    const int lrow = lane >> 2, lk = (lane & 3) * 8;
    for (int kt = 0; kt < NH; kt += 32) {
      {
        int row = m0 + wave * 16 + lrow;
        gload_lds16(fsrc + (long)row * NH + kt + lk, As + wave * 512);
        gload_lds16(w3b + (long)(n0 + wave * 16 + lrow) * NH + kt + lk, Bs + wave * 512);
      }
      __syncthreads();
      bf16x8 av[2], bv[4];
#pragma unroll
      for (int i = 0; i < 2; ++i) {
        int row = wr * 32 + i * 16 + (lane & 15);
        av[i] = *(const bf16x8*)(As + row * 32 + (lane >> 4) * 8);
      }
#pragma unroll
      for (int j = 0; j < 4; ++j) {
        int col = wc * 64 + j * 16 + (lane & 15);
        bv[j] = *(const bf16x8*)(Bs + col * 32 + (lane >> 4) * 8);
      }
#pragma unroll
      for (int i = 0; i < 2; ++i)
#pragma unroll
        for (int j = 0; j < 4; ++j)
          acc[i][j] = __builtin_amdgcn_mfma_f32_16x16x32_bf16(av[i], bv[j], acc[i][j], 0, 0, 0);
      __syncthreads();
    }
#pragma unroll
    for (int i = 0; i < 2; ++i)
#pragma unroll
      for (int j = 0; j < 4; ++j) {
        int gcol = n0 + wc * 64 + j * 16 + fr;
        float bsum = b3[gcol];
#pragma unroll
        for (int r = 0; r < 4; ++r) {
          int gm = m0 + wr * 32 + i * 16 + fq * 4 + r;
          fc3out[(long)gm * NA + gcol] = acc[i][j][r] + bsum;
        }
      }
    return;
  }

  if (blockIdx.x >= 64) {
    // ============ gx GEMM for chunk k+1 (512 thr, 128x128 tile) — R16 verbatim ==========
    if (!do_next) return;
    const int idx = blockIdx.x - 64;
    const int m0 = (idx >> 5) * 128;
    const int n0 = (idx & 31) * 128;
    const int wr = wave >> 1, wc = wave & 1;
    short* As = (short*)smem;
    short* Bs = (short*)smem + 128 * 32;
    f32x4 zero = {0.f, 0.f, 0.f, 0.f};
    f32x4 acc[2][4];
#pragma unroll
    for (int i = 0; i < 2; ++i)
#pragma unroll
      for (int j = 0; j < 4; ++j) acc[i][j] = zero;
    const int lrow = lane >> 2, lk = (lane & 3) * 8;
    const int t1 = t0 + C64;
    for (int kt = 0; kt < NH; kt += 32) {
      {
        int row = m0 + wave * 16 + lrow;
        long arow = (long)(row >> 6) * NTT + t1 + (row & 63);
        gload_lds16(fsrc + arow * NH + kt + lk, As + wave * 512);
        gload_lds16(wihb + (long)(n0 + wave * 16 + lrow) * NH + kt + lk, Bs + wave * 512);
      }
      __syncthreads();
      bf16x8 av[2], bv[4];
#pragma unroll
      for (int i = 0; i < 2; ++i) {
        int row = wr * 32 + i * 16 + (lane & 15);
        av[i] = *(const bf16x8*)(As + row * 32 + (lane >> 4) * 8);
      }
#pragma unroll
      for (int j = 0; j < 4; ++j) {
        int col = wc * 64 + j * 16 + (lane & 15);
        bv[j] = *(const bf16x8*)(Bs + col * 32 + (lane >> 4) * 8);
      }
#pragma unroll
      for (int i = 0; i < 2; ++i)
#pragma unroll
        for (int j = 0; j < 4; ++j)
          acc[i][j] = __builtin_amdgcn_mfma_f32_16x16x32_bf16(av[i], bv[j], acc[i][j], 0, 0, 0);
      __syncthreads();
    }
#pragma unroll
    for (int i = 0; i < 2; ++i)
#pragma unroll
      for (int j = 0; j < 4; ++j) {
        int gcol = n0 + wc * 64 + j * 16 + fr;
        float bsum = b_ih[gcol] + b_hh[gcol];
        int wgp = (gcol >> 4) & 63, gg = gcol >> 10, u = gcol & 15;
#pragma unroll
        for (int r = 0; r < 4; ++r) {
          int gm = m0 + wr * 32 + i * 16 + fq * 4 + r;
          int b = gm >> 6, tl = gm & 63;
          gxn[((((long)tl * 64 + wgp) * 64 + b) << 6) + gg * 16 + u] = f2bf(acc[i][j][r] + bsum);
        }
      }
    return;
  }

  // ================= scan (R14/R16 structure verbatim, C=64) =================
  float* pre = (float*)(smem + 64 * NH * 2);
  const int wg = blockIdx.x;
  const int g = wave >> 2, w2 = wave & 3;

  for (int idx = tid; idx < 64 * 128; idx += 512) {
    int n = idx >> 7, kc = idx & 127;
    int grow = (n >> 4) * NH + wg * 16 + (n & 15);
    bf16x8 w = *(const bf16x8*)(whh + (long)grow * NH + kc * 8);
    int frag = ((kc >> 2) * 4 + (n >> 4)) * 64 + (kc & 3) * 16 + (n & 15);
    *(bf16x8*)(smem + frag * 16) = w;
  }
  const int cb = tid >> 3, cup = tid & 7;
  float c0, c1;
  if (t0 == 0) {
    uint_t* p = (uint_t*)(hseq + cb * NH + wg * 16 + cup * 2);
    __hip_atomic_store(p, 0u, __ATOMIC_RELAXED, __HIP_MEMORY_SCOPE_AGENT);
    c0 = 0.f; c1 = 0.f;
  } else {
    c0 = cbuf[cb * NH + wg * 16 + cup * 2];
    c1 = cbuf[cb * NH + wg * 16 + cup * 2 + 1];
  }

  const int bb = w2 * 16;
  const int abrow = bb + fr;
  const int lane16 = lane * 16;
  f32x4 zero = {0.f, 0.f, 0.f, 0.f};

  ushort_t gxr[16];
  auto prefetch = [&](int tl) {
#pragma unroll
    for (int nt = 0; nt < 4; ++nt)
#pragma unroll
      for (int r = 0; r < 4; ++r)
        gxr[nt * 4 + r] =
            gxc[((((long)tl * 64 + wg) * 64 + (bb + fq * 4 + r)) << 6) + nt * 16 + fr];
  };
  auto poll = [&](uint_t t) {
    if (tid < 64) {
      uint_t* fp = flags + tid * 32;
      for (;;) {
        uint_t v = __hip_atomic_load(fp, __ATOMIC_RELAXED, __HIP_MEMORY_SCOPE_AGENT);
        if (__all(v >= t)) break;
        __builtin_amdgcn_s_sleep(1);
      }
    }
  };

  asm volatile("s_waitcnt vmcnt(0)" ::: "memory");
  __syncthreads();
  if (tid == 0)
    __hip_atomic_store(flags + wg * 32, tbase + 1, __ATOMIC_RELAXED, __HIP_MEMORY_SCOPE_AGENT);
  poll(tbase + 1);
  __builtin_amdgcn_fence(__ATOMIC_ACQUIRE, "agent");
  __syncthreads();
  if (g == 0) prefetch(0);

  for (int tl = 0; tl < C64; ++tl) {
    const ushort_t* hc = hseq + (size_t)tl * (NB * NH);
    bf16x8 areg[16];
#pragma unroll
    for (int ks = 0; ks < 16; ++ks) {
      int ksg = g * 16 + ((ks + wg) & 15);
      areg[ks] = *(const bf16x8*)(hc + abrow * NH + ksg * 32 + fq * 8);
    }
    __builtin_amdgcn_sched_barrier(0);

    f32x4 acc[4] = {zero, zero, zero, zero};
#pragma unroll
    for (int ks = 0; ks < 16; ++ks) {
      int ksg = g * 16 + ((ks + wg) & 15);
#pragma unroll
      for (int nt = 0; nt < 4; ++nt) {
        bf16x8 w = *(const bf16x8*)(smem + ((ksg * 4 + nt) << 10) + lane16);
        acc[nt] = __builtin_amdgcn_mfma_f32_16x16x32_bf16(areg[ks], w, acc[nt], 0, 0, 0);
      }
    }
    if (g == 1) {
#pragma unroll
      for (int nt = 0; nt < 4; ++nt)
#pragma unroll
        for (int r = 0; r < 4; ++r)
          pre[(bb + fq * 4 + r) * 64 + nt * 16 + fr] = acc[nt][r];
    }
    __syncthreads();
    if (g == 0) {
#pragma unroll
      for (int nt = 0; nt < 4; ++nt)
#pragma unroll
        for (int r = 0; r < 4; ++r) {
          int ii = (bb + fq * 4 + r) * 64 + nt * 16 + fr;
          pre[ii] = pre[ii] + acc[nt][r] + bf2f(gxr[nt * 4 + r]);
        }
    }
    __syncthreads();
    float h01[2];
#pragma unroll
    for (int k = 0; k < 2; ++k) {
      int u = cup * 2 + k;
      float xi = pre[cb * 64 + 0 * 16 + u];
      float xf = pre[cb * 64 + 1 * 16 + u];
      float xg = pre[cb * 64 + 2 * 16 + u];
      float xo = pre[cb * 64 + 3 * 16 + u];
      float ig = 1.f / (1.f + __expf(-xi));
      float fg = 1.f / (1.f + __expf(-xf));
      float gg = tanh_f(xg);
      float og = 1.f / (1.f + __expf(-xo));
      float& c = k ? c1 : c0;
      c = fg * c + ig * gg;
      h01[k] = og * tanh_f(c);
    }
    uint_t hpack = (uint_t)f2bf(h01[0]) | ((uint_t)f2bf(h01[1]) << 16);
    uint_t* hdst = (uint_t*)(hseq + (size_t)(tl + 1) * (NB * NH) + cb * NH + wg * 16 + cup * 2);
    __hip_atomic_store(hdst, hpack, __ATOMIC_RELAXED, __HIP_MEMORY_SCOPE_AGENT);
    if (tl == C64 - 1) {
      uint_t* h0 = (uint_t*)(hseq + cb * NH + wg * 16 + cup * 2);
      __hip_atomic_store(h0, hpack, __ATOMIC_RELAXED, __HIP_MEMORY_SCOPE_AGENT);
    }

    asm volatile("s_waitcnt vmcnt(0)" ::: "memory");
    __syncthreads();
    uint_t t = tbase + 2 + tl;
    if (tid == 0)
      __hip_atomic_store(flags + wg * 32, t, __ATOMIC_RELAXED, __HIP_MEMORY_SCOPE_AGENT);
    *(uint_t*)(hs + ((size_t)cb * NTT + t0 + tl) * NH + wg * 16 + cup * 2) = hpack;
    if (g == 0 && tl + 1 < C64) prefetch(tl + 1);
    poll(t);
    __syncthreads();
    asm volatile("" ::: "memory");
  }
  cbuf[cb * NH + wg * 16 + cup * 2] = c0;
  cbuf[cb * NH + wg * 16 + cup * 2 + 1] = c1;
}

// ---------------- host ----------------
extern "C" void kernel_launch(void* const* d_in, const int* in_sizes, int n_in,
                              void* d_out, int out_size, void* d_ws, size_t ws_size,
                              hipStream_t stream) {
  const float* x = (const float*)d_in[0];
  const float* w1 = (const float*)d_in[1];
  const float* b1 = (const float*)d_in[2];
  const float* w_ih = (const float*)d_in[3];
  const float* w_hh = (const float*)d_in[4];
  const float* b_ih = (const float*)d_in[5];
  const float* b_hh = (const float*)d_in[6];
  const float* w3 = (const float*)d_in[7];
  const float* b3 = (const float*)d_in[8];

  char* ws = (char*)d_ws;
  size_t off = 0;
  auto alloc = [&](size_t bytes) {
    char* p = ws + off;
    off += (bytes + 255) & ~(size_t)255;
    return p;
  };
  ushort_t* w1b = (ushort_t*)alloc(sizeof(ushort_t) * NH * NI);
  ushort_t* wihb = (ushort_t*)alloc(sizeof(ushort_t) * NG * NH);
  ushort_t* whhb = (ushort_t*)alloc(sizeof(ushort_t) * NG * NH);
  ushort_t* w3b = (ushort_t*)alloc(sizeof(ushort_t) * NA * NH);
  ushort_t* fb = (ushort_t*)alloc(sizeof(ushort_t) * (size_t)NB * NTT * NH);
  float* cbuf = (float*)alloc(sizeof(float) * NB * NH);
  uint_t* flags = (uint_t*)alloc(sizeof(uint_t) * 64 * 32);
  size_t off_small = off;
  ushort_t* gxcA = (ushort_t*)alloc(sizeof(ushort_t) * (size_t)C64 * 64 * NB * 64);
  ushort_t* gxcB = (ushort_t*)alloc(sizeof(ushort_t) * (size_t)C64 * 64 * NB * 64);
  size_t off_mid = off;
  ushort_t* hseq_ws = (ushort_t*)alloc(sizeof(ushort_t) * (size_t)(C64 + 1) * NB * NH);
  bool full = (off <= ws_size);        // hseq in ws -> fc3 fusion allowed
  bool mid = (off_mid <= ws_size);     // gx double-buffer in ws -> gx fusion (R16)
  if (!mid && off_small > ws_size) {
    hipMemsetAsync(d_out, 0xFF, 256, stream);  // NaN sentinel: ws too small even for base
    return;
  }

  // d_out scratch (dead before any fc3 writes land):
  ushort_t* xb = (ushort_t*)d_out;                                 // bf16 x (33.5MB)
  ushort_t* hseq = full ? hseq_ws : (ushort_t*)d_out;              // [65][NB][NH]
  ushort_t* gxc_small = (ushort_t*)d_out + (size_t)NB * NTT * NI;  // fallback gx

  auto cast = [&](const float* src, ushort_t* dst, int n) {
    cast_f32_bf16<<<dim3((n / 4 + 255) / 256), dim3(256), 0, stream>>>(src, dst, n);
  };
  cast(x, xb, NB * NTT * NI);
  cast(w1, w1b, NH * NI);
  cast(w_ih, wihb, NG * NH);
  cast(w_hh, whhb, NG * NH);
  cast(w3, w3b, NA * NH);

  hipMemsetAsync(flags, 0, sizeof(uint_t) * 64 * 32, stream);
  int ldsz = 64 * NH * 2 + 64 * 64 * 4;  // 144 KB
  hipFuncSetAttribute(reinterpret_cast<const void*>(&scan_fused),
                      hipFuncAttributeMaxDynamicSharedMemorySize, ldsz);

  if (mid) {
    // fc1 part1 (t<128) -> then fc1-rest || gx0 concurrently
    gemm_nt<1, 6><<<dim3(NH / 128, 64), dim3(256), 0, stream>>>(
        (const short*)xb, (const short*)w1b, b1, nullptr, fb, NH, NI, 0, 4, 0);
    fused_pre<<<dim3(1536 + 1024), dim3(256), 0, stream>>>(
        (const short*)xb, (const short*)w1b, b1, fb, (const short*)wihb, b_ih, b_hh, gxcA);

    for (int chunk = 0; chunk < NTT / C64; ++chunk) {
      int t0 = chunk * C64;
      ushort_t* cur = (chunk & 1) ? gxcB : gxcA;
      ushort_t* nxt = (chunk & 1) ? gxcA : gxcB;
      int do_next = (chunk + 1 < NTT / C64) ? 1 : 0;
      int do_fc3 = (full && chunk >= 2 && (chunk & 1) == 0) ? 1 : 0;
      int nblocks = do_fc3 ? 1344 : (do_next ? 1088 : 64);
      scan_fused<<<dim3(nblocks), dim3(512), ldsz, stream>>>(
          whhb, cur, (const short*)fb, wihb, b_ih, b_hh, nxt,
          w3b, b3, (float*)d_out, hseq, cbuf, fb, flags, t0,
          (uint_t)(chunk * 65), do_next, do_fc3);
    }
    if (full) {
      // remaining fc3: t in [384, 512) (tq = 3)
      gemm_nt<0, 6><<<dim3(NA / 128, 64), dim3(256), 0, stream>>>(
          (const short*)fb, (const short*)w3b, b3, nullptr, d_out, NA, NH, 0, 4, 3);
    } else {
      gemm_nt<0, 6><<<dim3(NA / 128, NB * NTT / 128), dim3(256), 0, stream>>>(
          (const short*)fb, (const short*)w3b, b3, nullptr, d_out, NA, NH, 0, 1, 0);
    }
  } else {
    // fallback: non-fused C=64 path, gx in d_out
    gemm_nt<1, 6><<<dim3(NH / 128, NB * NTT / 128), dim3(256), 0, stream>>>(
        (const short*)xb, (const short*)w1b, b1, nullptr, fb, NH, NI, 0, 1, 0);
    for (int chunk = 0; chunk < NTT / C64; ++chunk) {
      int t0 = chunk * C64;
      gemm_nt<2, 6><<<dim3(NG / 128, NB * C64 / 128), dim3(256), 0, stream>>>(
          (const short*)fb, (const short*)wihb, b_ih, b_hh, gxc_small, NG, NH, t0, 1, 0);
      scan_fused<<<dim3(64), dim3(512), ldsz, stream>>>(
          whhb, gxc_small, (const short*)fb, wihb, b_ih, b_hh, gxc_small,
          w3b, b3, (float*)d_out, hseq, cbuf, fb, flags, t0,
          (uint_t)(chunk * 65), 0, 0);
    }
    gemm_nt<0, 6><<<dim3(NA / 128, NB * NTT / 128), dim3(256), 0, stream>>>(
        (const short*)fb, (const short*)w3b, b3, nullptr, d_out, NA, NH, 0, 1, 0);
  }
}